// Round 2
// baseline (25769.092 us; speedup 1.0000x reference)
//
#include <hip/hip_runtime.h>
#include <hip/hip_bf16.h>
#include <stdint.h>
#include <math.h>

// Problem constants (fixed by the reference)
#define SEQ    2048
#define EMB    1024
#define HID    1024
#define G4     4096      // 4*HID
#define NEMO   16
#define NLAB   7

// LSTM persistent-kernel partition: 128 blocks x 256 threads.
// Block b owns 8 hidden units -> 32 gate rows (4 gates x 8 units).
// Thread t: wave wv = t>>6 handles rows {wv, wv+4, ..., wv+28} over h-columns
// [lane*16, lane*16+16). W fragment = 8x16 = 128 VGPRs.
#define NB 128

__device__ __forceinline__ float fsig(float x) { return 1.0f / (1.0f + __expf(-x)); }
__device__ __forceinline__ float ftanh(float x) {
    float ax = fabsf(x);
    float e  = __expf(-2.0f * ax);
    float t  = (1.0f - e) / (1.0f + e);
    return copysignf(t, x);
}

// ---------------- k_init: emoji average + htag reset ----------------
__global__ void k_init(const int* __restrict__ emoji_ids,
                       const float* __restrict__ emoji_emb,
                       float* __restrict__ eave,
                       unsigned long long* __restrict__ htag)
{
    int t = threadIdx.x;
    int ids[NEMO];
#pragma unroll
    for (int n = 0; n < NEMO; ++n) ids[n] = emoji_ids[n];
    for (int e = t; e < EMB; e += 256) {
        float s = 0.f;
#pragma unroll
        for (int n = 0; n < NEMO; ++n) s += emoji_emb[(size_t)ids[n] * EMB + e];
        eave[e] = s * (1.0f / 16.0f);
    }
    // htag[2][HID]: tag=0, value=0.0f  (h_{-1} = zeros, parity-1 buffer)
    for (int i = t; i < 2 * HID; i += 256) htag[i] = 0ull;
}

// ---------------- k_cvec: cvec = comb_W[:,1024:] @ eave + comb_b ----------------
__global__ void k_cvec(const float* __restrict__ combW,
                       const float* __restrict__ combB,
                       const float* __restrict__ eave,
                       float* __restrict__ cvec)
{
    // 64 blocks x 256 threads = 256 waves; 4 rows per wave
    int gw   = (blockIdx.x * 256 + threadIdx.x) >> 6;
    int lane = threadIdx.x & 63;
#pragma unroll
    for (int rr = 0; rr < 4; ++rr) {
        int r = gw * 4 + rr;
        const float* wrow = combW + (size_t)r * 2048 + 1024;
        float s = 0.f;
        for (int k = lane; k < EMB; k += 64) s = fmaf(wrow[k], eave[k], s);
#pragma unroll
        for (int off = 1; off < 64; off <<= 1) s += __shfl_xor(s, off);
        if (lane == 0) cvec[r] = s + combB[r];
    }
}

// ---------------- k_gemm: O[m][n] = sum_k Arow(m)[k]*B[n*bstride+k] + bias (+relu) ----
// BM=BN=128, BK=16, 256 threads, 8x8 microtile. K fixed at 1024, dims divide evenly.
__global__ __launch_bounds__(256) void k_gemm(
    const float* __restrict__ Asrc,
    const int*   __restrict__ ids,       // if non-null: A row m = emb[ids[m]]
    const float* __restrict__ emb,
    const float* __restrict__ B, int bstride,
    const float* __restrict__ bias1,
    const float* __restrict__ bias2,     // optional second bias
    float* __restrict__ O, int N, int relu)
{
    __shared__ float As[16][128];
    __shared__ float Bs[16][128];
    const int tid  = threadIdx.x;
    const int row0 = blockIdx.y * 128;
    const int col0 = blockIdx.x * 128;
    const int lr = tid >> 2;     // 0..63: staging row
    const int kq = tid & 3;      // 0..3 : k quad
    const float *ar0, *ar1;
    if (ids) {
        ar0 = emb + (size_t)ids[row0 + lr]      * 1024;
        ar1 = emb + (size_t)ids[row0 + lr + 64] * 1024;
    } else {
        ar0 = Asrc + (size_t)(row0 + lr)      * 1024;
        ar1 = Asrc + (size_t)(row0 + lr + 64) * 1024;
    }
    const float* br0 = B + (size_t)(col0 + lr)      * bstride;
    const float* br1 = B + (size_t)(col0 + lr + 64) * bstride;
    const int tx = tid & 15, ty = tid >> 4;

    float acc[8][8];
#pragma unroll
    for (int i = 0; i < 8; ++i)
#pragma unroll
        for (int j = 0; j < 8; ++j) acc[i][j] = 0.f;

    for (int k0 = 0; k0 < 1024; k0 += 16) {
        float4 a0 = *(const float4*)(ar0 + k0 + kq * 4);
        float4 a1 = *(const float4*)(ar1 + k0 + kq * 4);
        float4 b0 = *(const float4*)(br0 + k0 + kq * 4);
        float4 b1 = *(const float4*)(br1 + k0 + kq * 4);
        __syncthreads();
        {
            const float* pa0 = &a0.x; const float* pa1 = &a1.x;
            const float* pb0 = &b0.x; const float* pb1 = &b1.x;
#pragma unroll
            for (int e = 0; e < 4; ++e) {
                As[kq * 4 + e][lr]      = pa0[e];
                As[kq * 4 + e][lr + 64] = pa1[e];
                Bs[kq * 4 + e][lr]      = pb0[e];
                Bs[kq * 4 + e][lr + 64] = pb1[e];
            }
        }
        __syncthreads();
#pragma unroll
        for (int kk = 0; kk < 16; ++kk) {
            float af[8], bf[8];
            *(float4*)(af)     = *(const float4*)&As[kk][ty * 8];
            *(float4*)(af + 4) = *(const float4*)&As[kk][ty * 8 + 4];
            *(float4*)(bf)     = *(const float4*)&Bs[kk][tx * 8];
            *(float4*)(bf + 4) = *(const float4*)&Bs[kk][tx * 8 + 4];
#pragma unroll
            for (int i = 0; i < 8; ++i)
#pragma unroll
                for (int j = 0; j < 8; ++j)
                    acc[i][j] = fmaf(af[i], bf[j], acc[i][j]);
        }
    }
    // epilogue
    float bv[8];
    *(float4*)(bv)     = *(const float4*)&bias1[col0 + tx * 8];
    *(float4*)(bv + 4) = *(const float4*)&bias1[col0 + tx * 8 + 4];
    if (bias2) {
        float b2[8];
        *(float4*)(b2)     = *(const float4*)&bias2[col0 + tx * 8];
        *(float4*)(b2 + 4) = *(const float4*)&bias2[col0 + tx * 8 + 4];
#pragma unroll
        for (int j = 0; j < 8; ++j) bv[j] += b2[j];
    }
#pragma unroll
    for (int i = 0; i < 8; ++i) {
        int m = row0 + ty * 8 + i;
        float o[8];
#pragma unroll
        for (int j = 0; j < 8; ++j) {
            float v = acc[i][j] + bv[j];
            o[j] = relu ? fmaxf(v, 0.f) : v;
        }
        *(float4*)&O[(size_t)m * N + col0 + tx * 8]     = *(float4*)(o);
        *(float4*)&O[(size_t)m * N + col0 + tx * 8 + 4] = *(float4*)(o + 4);
    }
}

// ---------------- k_lstm: persistent sequential scan (v2) ----------------
// htag[2][HID] slots: (tag<<32)|float_bits, agent-scope atomics (coherent across XCDs).
// Step s: reads parity (s+1)&1 expecting tag s; writes parity s&1 with tag s+1.
//
// v2 changes vs v1:
//  - Each thread polls the 16 slots its own FMA fragment needs (h[lane*16..+16))
//    directly from htag -> no LDS h-staging, no S1 barrier (2 barriers/step).
//  - Pipelined polling: two 16-load sets in flight, memory re-sampled every
//    ~half RTT instead of every full RTT.
//  - Cell state in registers (lanes t<8); fast __expf-based sigmoid/tanh.
__global__ __launch_bounds__(256, 1) void k_lstm(
    const float* __restrict__ Whh,     // [4096][1024]
    const float* __restrict__ Gin,     // [2048][4096] precomputed input-gate terms
    unsigned long long* __restrict__ htag)
{
    const int b    = blockIdx.x;    // 0..127, owns units [8b, 8b+8)
    const int t    = threadIdx.x;   // 0..255
    const int lane = t & 63;
    const int wv   = t >> 6;        // wave id 0..3

    // W_hh fragment: 8 rows (wv+4i), cols [lane*16, lane*16+16)
    float w[8][16];
#pragma unroll
    for (int i = 0; i < 8; ++i) {
        int r = wv + 4 * i;
        int grow = ((r >> 3) << 10) + (b << 3) + (r & 7);
        const float4* p = (const float4*)(Whh + (size_t)grow * HID + lane * 16);
#pragma unroll
        for (int q = 0; q < 4; ++q) {
            float4 a = p[q];
            w[i][4 * q + 0] = a.x; w[i][4 * q + 1] = a.y;
            w[i][4 * q + 2] = a.z; w[i][4 * q + 3] = a.w;
        }
    }

    __shared__ float red[32 * 72];    // per-row partials, padded stride 72
    __shared__ float gat[32];         // 32 gate pre-activations

    const int rr = t >> 3, kk = t & 7;          // reduction role
    const int growR = ((rr >> 3) << 10) + (b << 3) + (rr & 7);

    float creg = 0.f;                 // cell state, valid in lanes t<8

    for (int s = 0; s < SEQ; ++s) {
        // prefetch this step's G_in row term (independent of h)
        float gval = 0.f;
        if (kk == 0) gval = Gin[(size_t)s * G4 + growR];

        // ---- pipelined poll of h_{s-1}: own 16 slots, 2 load-sets in flight ----
        unsigned long long* src =
            htag + (size_t)(((unsigned)(s + 1)) & 1u) * HID + lane * 16;
        const unsigned expw = (unsigned)s;
        unsigned long long va[16], vb[16];
#pragma unroll
        for (int q = 0; q < 16; ++q)
            va[q] = __hip_atomic_load(src + q, __ATOMIC_RELAXED, __HIP_MEMORY_SCOPE_AGENT);
#pragma unroll
        for (int q = 0; q < 16; ++q)
            vb[q] = __hip_atomic_load(src + q, __ATOMIC_RELAXED, __HIP_MEMORY_SCOPE_AGENT);

        float hf[16];
        for (;;) {
            unsigned ok = 1u;
#pragma unroll
            for (int q = 0; q < 16; ++q) ok &= ((unsigned)(va[q] >> 32) == expw) ? 1u : 0u;
            if (__all((int)ok)) {
#pragma unroll
                for (int q = 0; q < 16; ++q) hf[q] = __uint_as_float((unsigned)va[q]);
                break;
            }
#pragma unroll
            for (int q = 0; q < 16; ++q)
                va[q] = __hip_atomic_load(src + q, __ATOMIC_RELAXED, __HIP_MEMORY_SCOPE_AGENT);
            ok = 1u;
#pragma unroll
            for (int q = 0; q < 16; ++q) ok &= ((unsigned)(vb[q] >> 32) == expw) ? 1u : 0u;
            if (__all((int)ok)) {
#pragma unroll
                for (int q = 0; q < 16; ++q) hf[q] = __uint_as_float((unsigned)vb[q]);
                break;
            }
#pragma unroll
            for (int q = 0; q < 16; ++q)
                vb[q] = __hip_atomic_load(src + q, __ATOMIC_RELAXED, __HIP_MEMORY_SCOPE_AGENT);
        }

        // ---- partial matvec: 8 rows x 16 cols per thread ----
        float p[8];
#pragma unroll
        for (int i = 0; i < 8; ++i) p[i] = 0.f;
#pragma unroll
        for (int j = 0; j < 16; ++j)
#pragma unroll
            for (int i = 0; i < 8; ++i)
                p[i] = fmaf(w[i][j], hf[j], p[i]);
#pragma unroll
        for (int i = 0; i < 8; ++i) red[(wv + 4 * i) * 72 + lane] = p[i];
        __syncthreads();   // S2: partials written

        float rs = 0.f;
#pragma unroll
        for (int j = 0; j < 8; ++j) rs += red[rr * 72 + j * 8 + kk];
        rs += __shfl_xor(rs, 1);
        rs += __shfl_xor(rs, 2);
        rs += __shfl_xor(rs, 4);
        if (kk == 0) gat[rr] = rs + gval;
        __syncthreads();   // S3: gates assembled

        if (t < 8) {
            float gi = gat[t], gf = gat[8 + t], gg = gat[16 + t], go = gat[24 + t];
            float c = fsig(gf) * creg + fsig(gi) * ftanh(gg);
            creg = c;
            float h = fsig(go) * ftanh(c);
            unsigned long long pk =
                ((unsigned long long)(unsigned)(s + 1) << 32) |
                (unsigned long long)__float_as_uint(h);
            __hip_atomic_store(htag + (size_t)(((unsigned)s) & 1u) * HID + b * 8 + t,
                               pk, __ATOMIC_RELAXED, __HIP_MEMORY_SCOPE_AGENT);
        }
        // No trailing barrier: next step's poll (gated by own-block store, which
        // follows all step-s LDS reads) + S2 protect red[]; S2 protects gat[].
    }
}

// ---------------- k_out: out = out_W @ h_final + out_b ----------------
__global__ void k_out(const float* __restrict__ outW,
                      const float* __restrict__ outb,
                      const unsigned long long* __restrict__ htag,
                      float* __restrict__ out)
{
    int wv = threadIdx.x >> 6, lane = threadIdx.x & 63;   // 7 waves
    if (wv < NLAB) {
        float s = 0.f;
        for (int k = lane; k < HID; k += 64) {
            float h = __uint_as_float((unsigned)(htag[HID + k] & 0xffffffffULL));
            s = fmaf(outW[wv * HID + k], h, s);
        }
#pragma unroll
        for (int off = 1; off < 64; off <<= 1) s += __shfl_xor(s, off);
        if (lane == 0) out[wv] = s + outb[wv];
    }
}

extern "C" void kernel_launch(void* const* d_in, const int* in_sizes, int n_in,
                              void* d_out, int out_size, void* d_ws, size_t ws_size,
                              hipStream_t stream)
{
    const int*   sent_ids = (const int*)  d_in[0];
    const int*   emo_ids  = (const int*)  d_in[1];
    const float* word_emb = (const float*)d_in[2];
    const float* emo_emb  = (const float*)d_in[3];
    // d_in[4] attn_W, d_in[5] attn_b: unused — softmax over a single logit == 1.0
    const float* comb_W   = (const float*)d_in[6];
    const float* comb_b   = (const float*)d_in[7];
    const float* W_ih     = (const float*)d_in[8];
    const float* W_hh     = (const float*)d_in[9];
    const float* b_ih     = (const float*)d_in[10];
    const float* b_hh     = (const float*)d_in[11];
    const float* out_W    = (const float*)d_in[12];
    const float* out_b    = (const float*)d_in[13];
    float* out = (float*)d_out;

    float* ws   = (float*)d_ws;
    float* eave = ws;                                   // 1024
    float* cvec = ws + 1024;                            // 1024 (pad to 4096)
    float* C    = ws + 4096;                            // 2048*1024
    float* G    = ws + 4096 + (size_t)SEQ * EMB;        // 2048*4096
    unsigned long long* htag =
        (unsigned long long*)(ws + 4096 + (size_t)SEQ * EMB + (size_t)SEQ * G4); // 2*1024 u64

    k_init<<<1, 256, 0, stream>>>(emo_ids, emo_emb, eave, htag);
    k_cvec<<<64, 256, 0, stream>>>(comb_W, comb_b, eave, cvec);
    // C = relu( gather(word_emb, sent_ids) @ W_x^T + cvec ),  W_x = comb_W[:, :1024]
    dim3 g1(EMB / 128, SEQ / 128);
    k_gemm<<<g1, 256, 0, stream>>>(nullptr, sent_ids, word_emb,
                                   comb_W, 2048, cvec, nullptr, C, EMB, 1);
    // G = C @ W_ih^T + b_ih + b_hh
    dim3 g2(G4 / 128, SEQ / 128);
    k_gemm<<<g2, 256, 0, stream>>>(C, nullptr, nullptr,
                                   W_ih, 1024, b_ih, b_hh, G, G4, 0);
    k_lstm<<<NB, 256, 0, stream>>>(W_hh, G, htag);
    k_out<<<1, 448, 0, stream>>>(out_W, out_b, htag, out);
}

// Round 3
// 12435.110 us; speedup vs baseline: 2.0723x; 2.0723x over previous
//
#include <hip/hip_runtime.h>
#include <hip/hip_bf16.h>
#include <stdint.h>
#include <math.h>

// Problem constants (fixed by the reference)
#define SEQ    2048
#define EMB    1024
#define HID    1024
#define G4     4096      // 4*HID
#define NEMO   16
#define NLAB   7

// LSTM persistent-kernel partition: 128 blocks x 256 threads.
// Block b owns 8 hidden units -> 32 gate rows (4 gates x 8 units).
#define NB 128
#define CSTRIDE 32   // counter stride in ints (128B) so polled line != RMW'd line

__device__ __forceinline__ float fsig(float x) { return 1.0f / (1.0f + __expf(-x)); }
__device__ __forceinline__ float ftanh(float x) {
    float ax = fabsf(x);
    float e  = __expf(-2.0f * ax);
    float t  = (1.0f - e) / (1.0f + e);
    return copysignf(t, x);
}

// ---------------- k_init: emoji average + hbuf/cnt reset ----------------
__global__ void k_init(const int* __restrict__ emoji_ids,
                       const float* __restrict__ emoji_emb,
                       float* __restrict__ eave,
                       float* __restrict__ hbuf,   // [2][HID]
                       int* __restrict__ cnt)      // [SEQ+1] stride CSTRIDE
{
    int t = threadIdx.x;
    int ids[NEMO];
#pragma unroll
    for (int n = 0; n < NEMO; ++n) ids[n] = emoji_ids[n];
    for (int e = t; e < EMB; e += 256) {
        float s = 0.f;
#pragma unroll
        for (int n = 0; n < NEMO; ++n) s += emoji_emb[(size_t)ids[n] * EMB + e];
        eave[e] = s * (1.0f / 16.0f);
    }
    // h_{-1} = 0 lives in parity-1 buffer
    for (int i = t; i < 2 * HID; i += 256) hbuf[i] = 0.f;
    // cnt[0] = NB (step -1 "already published"); cnt[1..SEQ] = 0
    for (int i = t; i <= SEQ; i += 256) cnt[(size_t)i * CSTRIDE] = (i == 0) ? NB : 0;
}

// ---------------- k_cvec: cvec = comb_W[:,1024:] @ eave + comb_b ----------------
__global__ void k_cvec(const float* __restrict__ combW,
                       const float* __restrict__ combB,
                       const float* __restrict__ eave,
                       float* __restrict__ cvec)
{
    int gw   = (blockIdx.x * 256 + threadIdx.x) >> 6;
    int lane = threadIdx.x & 63;
#pragma unroll
    for (int rr = 0; rr < 4; ++rr) {
        int r = gw * 4 + rr;
        const float* wrow = combW + (size_t)r * 2048 + 1024;
        float s = 0.f;
        for (int k = lane; k < EMB; k += 64) s = fmaf(wrow[k], eave[k], s);
#pragma unroll
        for (int off = 1; off < 64; off <<= 1) s += __shfl_xor(s, off);
        if (lane == 0) cvec[r] = s + combB[r];
    }
}

// ---------------- k_gemm: O[m][n] = sum_k Arow(m)[k]*B[n*bstride+k] + bias (+relu) ----
__global__ __launch_bounds__(256) void k_gemm(
    const float* __restrict__ Asrc,
    const int*   __restrict__ ids,       // if non-null: A row m = emb[ids[m]]
    const float* __restrict__ emb,
    const float* __restrict__ B, int bstride,
    const float* __restrict__ bias1,
    const float* __restrict__ bias2,     // optional second bias
    float* __restrict__ O, int N, int relu)
{
    __shared__ float As[16][128];
    __shared__ float Bs[16][128];
    const int tid  = threadIdx.x;
    const int row0 = blockIdx.y * 128;
    const int col0 = blockIdx.x * 128;
    const int lr = tid >> 2;     // 0..63: staging row
    const int kq = tid & 3;      // 0..3 : k quad
    const float *ar0, *ar1;
    if (ids) {
        ar0 = emb + (size_t)ids[row0 + lr]      * 1024;
        ar1 = emb + (size_t)ids[row0 + lr + 64] * 1024;
    } else {
        ar0 = Asrc + (size_t)(row0 + lr)      * 1024;
        ar1 = Asrc + (size_t)(row0 + lr + 64) * 1024;
    }
    const float* br0 = B + (size_t)(col0 + lr)      * bstride;
    const float* br1 = B + (size_t)(col0 + lr + 64) * bstride;
    const int tx = tid & 15, ty = tid >> 4;

    float acc[8][8];
#pragma unroll
    for (int i = 0; i < 8; ++i)
#pragma unroll
        for (int j = 0; j < 8; ++j) acc[i][j] = 0.f;

    for (int k0 = 0; k0 < 1024; k0 += 16) {
        float4 a0 = *(const float4*)(ar0 + k0 + kq * 4);
        float4 a1 = *(const float4*)(ar1 + k0 + kq * 4);
        float4 b0 = *(const float4*)(br0 + k0 + kq * 4);
        float4 b1 = *(const float4*)(br1 + k0 + kq * 4);
        __syncthreads();
        {
            const float* pa0 = &a0.x; const float* pa1 = &a1.x;
            const float* pb0 = &b0.x; const float* pb1 = &b1.x;
#pragma unroll
            for (int e = 0; e < 4; ++e) {
                As[kq * 4 + e][lr]      = pa0[e];
                As[kq * 4 + e][lr + 64] = pa1[e];
                Bs[kq * 4 + e][lr]      = pb0[e];
                Bs[kq * 4 + e][lr + 64] = pb1[e];
            }
        }
        __syncthreads();
#pragma unroll
        for (int kk = 0; kk < 16; ++kk) {
            float af[8], bf[8];
            *(float4*)(af)     = *(const float4*)&As[kk][ty * 8];
            *(float4*)(af + 4) = *(const float4*)&As[kk][ty * 8 + 4];
            *(float4*)(bf)     = *(const float4*)&Bs[kk][tx * 8];
            *(float4*)(bf + 4) = *(const float4*)&Bs[kk][tx * 8 + 4];
#pragma unroll
            for (int i = 0; i < 8; ++i)
#pragma unroll
                for (int j = 0; j < 8; ++j)
                    acc[i][j] = fmaf(af[i], bf[j], acc[i][j]);
        }
    }
    // epilogue
    float bv[8];
    *(float4*)(bv)     = *(const float4*)&bias1[col0 + tx * 8];
    *(float4*)(bv + 4) = *(const float4*)&bias1[col0 + tx * 8 + 4];
    if (bias2) {
        float b2[8];
        *(float4*)(b2)     = *(const float4*)&bias2[col0 + tx * 8];
        *(float4*)(b2 + 4) = *(const float4*)&bias2[col0 + tx * 8 + 4];
#pragma unroll
        for (int j = 0; j < 8; ++j) bv[j] += b2[j];
    }
#pragma unroll
    for (int i = 0; i < 8; ++i) {
        int m = row0 + ty * 8 + i;
        float o[8];
#pragma unroll
        for (int j = 0; j < 8; ++j) {
            float v = acc[i][j] + bv[j];
            o[j] = relu ? fmaxf(v, 0.f) : v;
        }
        *(float4*)&O[(size_t)m * N + col0 + tx * 8]     = *(float4*)(o);
        *(float4*)&O[(size_t)m * N + col0 + tx * 8 + 4] = *(float4*)(o + 4);
    }
}

// ---------------- k_lstm: persistent sequential scan (v3) ----------------
// Sync:  cnt[s+1] fetch_add(1, release) by each block after publishing h_s.
//        Reader at step s waits cnt[s] == NB (only wave 0 polls: same-address
//        wave load = 1 broadcast request/round -> tiny coherent-point traffic).
// Data:  hbuf[2][HID] plain floats, written/read with relaxed agent atomics
//        (bypass non-coherent per-XCD L2). Read exactly once per step.
__global__ __launch_bounds__(256, 1) void k_lstm(
    const float* __restrict__ Whh,     // [4096][1024]
    const float* __restrict__ Gin,     // [2048][4096] precomputed input-gate terms
    float* __restrict__ hbuf,          // [2][HID]
    int* __restrict__ cnt)             // [SEQ+1] stride CSTRIDE
{
    const int b    = blockIdx.x;    // 0..127, owns units [8b, 8b+8)
    const int t    = threadIdx.x;   // 0..255
    const int lane = t & 63;
    const int wv   = t >> 6;        // wave id 0..3

    // W_hh fragment: 8 rows (wv+4i), cols [lane*16, lane*16+16)
    float w[8][16];
#pragma unroll
    for (int i = 0; i < 8; ++i) {
        int r = wv + 4 * i;
        int grow = ((r >> 3) << 10) + (b << 3) + (r & 7);
        const float4* p = (const float4*)(Whh + (size_t)grow * HID + lane * 16);
#pragma unroll
        for (int q = 0; q < 4; ++q) {
            float4 a = p[q];
            w[i][4 * q + 0] = a.x; w[i][4 * q + 1] = a.y;
            w[i][4 * q + 2] = a.z; w[i][4 * q + 3] = a.w;
        }
    }

    __shared__ float red[32 * 72];    // per-row partials, padded stride 72
    __shared__ float gat[32];         // 32 gate pre-activations

    const int rr = t >> 3, kk = t & 7;          // reduction role
    const int growR = ((rr >> 3) << 10) + (b << 3) + (rr & 7);

    float creg = 0.f;                 // cell state, valid in lanes t<8

    for (int s = 0; s < SEQ; ++s) {
        // prefetch this step's G_in row term (independent of h; overlaps the wait)
        float gval = 0.f;
        if (kk == 0) gval = Gin[(size_t)s * G4 + growR];

        // ---- wait for h_{s-1}: wave 0 polls the step counter ----
        if (t < 64) {
            const int* cp = cnt + (size_t)s * CSTRIDE;
            while (__hip_atomic_load(cp, __ATOMIC_RELAXED, __HIP_MEMORY_SCOPE_AGENT) < NB) {}
            __builtin_amdgcn_fence(__ATOMIC_ACQUIRE, "agent");
        }
        __syncthreads();   // S1: release waves 1..3

        // ---- read own h fragment: h[lane*16 .. +16) as 8x 8B coherent loads ----
        const unsigned long long* hsrc =
            (const unsigned long long*)(hbuf + (size_t)(((unsigned)(s + 1)) & 1u) * HID) + lane * 8;
        float hf[16];
#pragma unroll
        for (int q = 0; q < 8; ++q) {
            unsigned long long v =
                __hip_atomic_load(hsrc + q, __ATOMIC_RELAXED, __HIP_MEMORY_SCOPE_AGENT);
            hf[2 * q]     = __uint_as_float((unsigned)v);
            hf[2 * q + 1] = __uint_as_float((unsigned)(v >> 32));
        }

        // ---- partial matvec: 8 rows x 16 cols per thread ----
        float p[8];
#pragma unroll
        for (int i = 0; i < 8; ++i) p[i] = 0.f;
#pragma unroll
        for (int j = 0; j < 16; ++j)
#pragma unroll
            for (int i = 0; i < 8; ++i)
                p[i] = fmaf(w[i][j], hf[j], p[i]);
#pragma unroll
        for (int i = 0; i < 8; ++i) red[(wv + 4 * i) * 72 + lane] = p[i];
        __syncthreads();   // S2: partials written

        float rs = 0.f;
#pragma unroll
        for (int j = 0; j < 8; ++j) rs += red[rr * 72 + j * 8 + kk];
        rs += __shfl_xor(rs, 1);
        rs += __shfl_xor(rs, 2);
        rs += __shfl_xor(rs, 4);
        if (kk == 0) gat[rr] = rs + gval;
        __syncthreads();   // S3: gates assembled

        if (t < 8) {
            float gi = gat[t], gf = gat[8 + t], gg = gat[16 + t], go = gat[24 + t];
            float c = fsig(gf) * creg + fsig(gi) * ftanh(gg);
            creg = c;
            float h = fsig(go) * ftanh(c);
            __hip_atomic_store(
                (unsigned*)hbuf + (size_t)(((unsigned)s) & 1u) * HID + b * 8 + t,
                __float_as_uint(h), __ATOMIC_RELAXED, __HIP_MEMORY_SCOPE_AGENT);
        }
        __syncthreads();   // S4: vmcnt(0) drain -> h stores visible before flag
        if (t == 0)
            __hip_atomic_fetch_add(cnt + (size_t)(s + 1) * CSTRIDE, 1,
                                   __ATOMIC_RELEASE, __HIP_MEMORY_SCOPE_AGENT);
    }
}

// ---------------- k_out: out = out_W @ h_final + out_b ----------------
// h_2047 lives in hbuf parity 1 (2047 & 1). Kernel boundary = full release,
// so plain loads are fine here.
__global__ void k_out(const float* __restrict__ outW,
                      const float* __restrict__ outb,
                      const float* __restrict__ hbuf,
                      float* __restrict__ out)
{
    int wv = threadIdx.x >> 6, lane = threadIdx.x & 63;   // 7 waves
    if (wv < NLAB) {
        float s = 0.f;
        for (int k = lane; k < HID; k += 64)
            s = fmaf(outW[wv * HID + k], hbuf[HID + k], s);
#pragma unroll
        for (int off = 1; off < 64; off <<= 1) s += __shfl_xor(s, off);
        if (lane == 0) out[wv] = s + outb[wv];
    }
}

extern "C" void kernel_launch(void* const* d_in, const int* in_sizes, int n_in,
                              void* d_out, int out_size, void* d_ws, size_t ws_size,
                              hipStream_t stream)
{
    const int*   sent_ids = (const int*)  d_in[0];
    const int*   emo_ids  = (const int*)  d_in[1];
    const float* word_emb = (const float*)d_in[2];
    const float* emo_emb  = (const float*)d_in[3];
    // d_in[4] attn_W, d_in[5] attn_b: unused — softmax over a single logit == 1.0
    const float* comb_W   = (const float*)d_in[6];
    const float* comb_b   = (const float*)d_in[7];
    const float* W_ih     = (const float*)d_in[8];
    const float* W_hh     = (const float*)d_in[9];
    const float* b_ih     = (const float*)d_in[10];
    const float* b_hh     = (const float*)d_in[11];
    const float* out_W    = (const float*)d_in[12];
    const float* out_b    = (const float*)d_in[13];
    float* out = (float*)d_out;

    float* ws   = (float*)d_ws;
    float* eave = ws;                                   // 1024
    float* cvec = ws + 1024;                            // 1024 (pad to 4096)
    float* C    = ws + 4096;                            // 2048*1024
    float* G    = ws + 4096 + (size_t)SEQ * EMB;        // 2048*4096
    float* hbuf = G + (size_t)SEQ * G4;                 // 2*1024 floats
    int*   cnt  = (int*)(hbuf + 2 * HID);               // (SEQ+1)*CSTRIDE ints

    k_init<<<1, 256, 0, stream>>>(emo_ids, emo_emb, eave, hbuf, cnt);
    k_cvec<<<64, 256, 0, stream>>>(comb_W, comb_b, eave, cvec);
    // C = relu( gather(word_emb, sent_ids) @ W_x^T + cvec ),  W_x = comb_W[:, :1024]
    dim3 g1(EMB / 128, SEQ / 128);
    k_gemm<<<g1, 256, 0, stream>>>(nullptr, sent_ids, word_emb,
                                   comb_W, 2048, cvec, nullptr, C, EMB, 1);
    // G = C @ W_ih^T + b_ih + b_hh
    dim3 g2(G4 / 128, SEQ / 128);
    k_gemm<<<g2, 256, 0, stream>>>(C, nullptr, nullptr,
                                   W_ih, 1024, b_ih, b_hh, G, G4, 0);
    k_lstm<<<NB, 256, 0, stream>>>(W_hh, G, hbuf, cnt);
    k_out<<<1, 448, 0, stream>>>(out_W, out_b, hbuf, out);
}